// Round 4
// baseline (344.766 us; speedup 1.0000x reference)
//
#include <hip/hip_runtime.h>
#include <math.h>

#define EPS 1e-7f

// Native clang vector type — required for __builtin_nontemporal_load.
typedef float f32x4 __attribute__((ext_vector_type(4)));

// Scalar online-softmax update (edge paths only).
__device__ __forceinline__ void online_upd(float x, float& m, float& s) {
    if (x > m) {
        s *= __expf(m - x);
        m = x;
    }
    s += __expf(x - m);
}

// Amortized float4 update: ONE max-compare per 4 elements, 4 independent
// exps, tree-summed. Excludes target column when it falls in this float4.
__device__ __forceinline__ void upd4(const f32x4 x4, int e, int t,
                                     float& m, float& s) {
    if ((unsigned)(t - e) > 3u) {          // common case: target not here
        const float lm = fmaxf(fmaxf(x4.x, x4.y), fmaxf(x4.z, x4.w));
        if (lm > m) {
            s *= __expf(m - lm);           // s==0 first time: exp(-inf)=0 ok
            m = lm;
        }
        const float e0 = __expf(x4.x - m);
        const float e1 = __expf(x4.y - m);
        const float e2 = __expf(x4.z - m);
        const float e3 = __expf(x4.w - m);
        s += (e0 + e1) + (e2 + e3);
    } else {                               // rare: exclude target element
        if (e + 0 != t) online_upd(x4.x, m, s);
        if (e + 1 != t) online_upd(x4.y, m, s);
        if (e + 2 != t) online_upd(x4.z, m, s);
        if (e + 3 != t) online_upd(x4.w, m, s);
    }
}

// Merge (mo, so) into (m, s). Safe when exactly one side is empty
// (m=-inf, s=0): exp(-inf)=0 kills the empty term.
__device__ __forceinline__ void merge(float mo, float so, float& m, float& s) {
    const float mn = fmaxf(m, mo);
    s = s * __expf(m - mn) + so * __expf(mo - mn);
    m = mn;
}

// Fused: one block per row computes the row loss; the LAST block to finish
// (device-scope atomic ticket) deterministically sums all row losses and
// writes the mean. Counter is zeroed per-launch by hipMemsetAsync.
__global__ __launch_bounds__(256) void cml_fused_kernel(
        const float* __restrict__ in, const int* __restrict__ target,
        float* __restrict__ row_loss, unsigned* __restrict__ counter,
        float* __restrict__ out, int C, int B) {
    const int row = blockIdx.x;
    const int tid = threadIdx.x;
    const size_t base = (size_t)row * (size_t)C;
    const float* __restrict__ rowp = in + base;
    const int t = target[row];

    float m0 = -INFINITY, s0 = 0.0f;
    float m1 = -INFINITY, s1 = 0.0f;
    float m2 = -INFINITY, s2 = 0.0f;
    float m3 = -INFINITY, s3 = 0.0f;

    // Scalar prologue to 16B alignment (base % 4 == row % 4, C odd).
    const int pre = (4 - (int)(base & 3)) & 3;
    if (tid < pre) {
        if (tid != t) online_upd(rowp[tid], m0, s0);
    }

    const int nv = (C - pre) >> 2;  // aligned float4 count (~12564)
    const f32x4* __restrict__ v = reinterpret_cast<const f32x4*>(rowp + pre);

    // Unroll-4, four independent accumulator pairs (load + s-chain ILP).
    int j = tid;
    for (; j + 768 < nv; j += 1024) {
        const f32x4 a = __builtin_nontemporal_load(&v[j]);
        const f32x4 b = __builtin_nontemporal_load(&v[j + 256]);
        const f32x4 c = __builtin_nontemporal_load(&v[j + 512]);
        const f32x4 d = __builtin_nontemporal_load(&v[j + 768]);
        upd4(a, pre + (j << 2),         t, m0, s0);
        upd4(b, pre + ((j + 256) << 2), t, m1, s1);
        upd4(c, pre + ((j + 512) << 2), t, m2, s2);
        upd4(d, pre + ((j + 768) << 2), t, m3, s3);
    }
    for (; j < nv; j += 256) {
        const f32x4 a = __builtin_nontemporal_load(&v[j]);
        upd4(a, pre + (j << 2), t, m0, s0);
    }

    // Scalar tail.
    for (int k = pre + (nv << 2) + tid; k < C; k += 256) {
        if (k != t) online_upd(rowp[k], m0, s0);
    }

    // Merge the 4 accumulators (every thread touched all 4 for C=50257).
    merge(m1, s1, m0, s0);
    merge(m3, s3, m2, s2);
    merge(m2, s2, m0, s0);

    // Wave butterfly reduce of (m0, s0).
    #pragma unroll
    for (int off = 32; off > 0; off >>= 1) {
        const float mo = __shfl_xor(m0, off, 64);
        const float so = __shfl_xor(s0, off, 64);
        merge(mo, so, m0, s0);
    }

    // Cross-wave combine via LDS (4 waves).
    __shared__ float sm[4];
    __shared__ float ss[4];
    if ((tid & 63) == 0) {
        sm[tid >> 6] = m0;
        ss[tid >> 6] = s0;
    }
    __syncthreads();

    if (tid == 0) {
        float M = sm[0], S = ss[0];
        #pragma unroll
        for (int w = 1; w < 4; ++w) merge(sm[w], ss[w], M, S);
        // M = max over non-target, S = sum exp(x - M) over non-target.
        const float xt = rowp[t];
        const float mf = fmaxf(M, xt);
        const float Sf = S * __expf(M - mf) + __expf(xt - mf);
        const float p_t  = __expf(xt - mf) / Sf;
        const float p_mi = __expf(M - mf) / Sf;
        row_loss[row] = -logf(p_t + EPS) - logf(1.0f - p_mi + EPS);
    }

    // ---- last-block deterministic mean ----
    __shared__ bool is_last;
    if (tid == 0) {
        __threadfence();                       // row_loss[row] visible device-wide
        const unsigned ticket = atomicAdd(counter, 1u);
        is_last = (ticket == (unsigned)(B - 1));
    }
    __syncthreads();
    if (is_last) {
        __threadfence();                       // see all blocks' row_loss
        float s = 0.0f;
        for (int i = tid; i < B; i += 256) s += row_loss[i];
        #pragma unroll
        for (int off = 32; off > 0; off >>= 1) s += __shfl_xor(s, off, 64);
        __shared__ float sw[4];
        if ((tid & 63) == 0) sw[tid >> 6] = s;
        __syncthreads();
        if (tid == 0) out[0] = (sw[0] + sw[1] + sw[2] + sw[3]) / (float)B;
    }
}

// Fallback pair (used only if ws_size is too small for the counter).
__global__ __launch_bounds__(256) void cml_row_kernel(
        const float* __restrict__ in, const int* __restrict__ target,
        float* __restrict__ row_loss, int C) {
    const int row = blockIdx.x;
    const int tid = threadIdx.x;
    const size_t base = (size_t)row * (size_t)C;
    const float* __restrict__ rowp = in + base;
    const int t = target[row];
    float m0 = -INFINITY, s0 = 0.0f;
    for (int k = tid; k < C; k += 256) {
        if (k != t) online_upd(rowp[k], m0, s0);
    }
    #pragma unroll
    for (int off = 32; off > 0; off >>= 1) {
        const float mo = __shfl_xor(m0, off, 64);
        const float so = __shfl_xor(s0, off, 64);
        merge(mo, so, m0, s0);
    }
    __shared__ float sm[4];
    __shared__ float ss[4];
    if ((tid & 63) == 0) { sm[tid >> 6] = m0; ss[tid >> 6] = s0; }
    __syncthreads();
    if (tid == 0) {
        float M = sm[0], S = ss[0];
        #pragma unroll
        for (int w = 1; w < 4; ++w) merge(sm[w], ss[w], M, S);
        const float xt = rowp[t];
        const float mf = fmaxf(M, xt);
        const float Sf = S * __expf(M - mf) + __expf(xt - mf);
        row_loss[row] = -logf(__expf(xt - mf) / Sf + EPS)
                        - logf(1.0f - __expf(M - mf) / Sf + EPS);
    }
}

__global__ __launch_bounds__(256) void cml_mean_kernel(
        const float* __restrict__ row_loss, float* __restrict__ out, int B) {
    const int tid = threadIdx.x;
    float s = 0.0f;
    for (int i = tid; i < B; i += 256) s += row_loss[i];
    #pragma unroll
    for (int off = 32; off > 0; off >>= 1) s += __shfl_xor(s, off, 64);
    __shared__ float sw[4];
    if ((tid & 63) == 0) sw[tid >> 6] = s;
    __syncthreads();
    if (tid == 0) out[0] = (sw[0] + sw[1] + sw[2] + sw[3]) / (float)B;
}

extern "C" void kernel_launch(void* const* d_in, const int* in_sizes, int n_in,
                              void* d_out, int out_size, void* d_ws, size_t ws_size,
                              hipStream_t stream) {
    const float* in = (const float*)d_in[0];
    const int* target = (const int*)d_in[1];
    const int B = in_sizes[1];                 // 4096
    const int C = in_sizes[0] / B;             // 50257
    float* row_loss = (float*)d_ws;            // B floats
    const size_t need = (size_t)B * sizeof(float) + sizeof(unsigned);

    if (ws_size >= need) {
        unsigned* counter = (unsigned*)((char*)d_ws + (size_t)B * sizeof(float));
        hipMemsetAsync(counter, 0, sizeof(unsigned), stream);
        cml_fused_kernel<<<B, 256, 0, stream>>>(in, target, row_loss, counter,
                                                (float*)d_out, C, B);
    } else {
        cml_row_kernel<<<B, 256, 0, stream>>>(in, target, row_loss, C);
        cml_mean_kernel<<<1, 256, 0, stream>>>(row_loss, (float*)d_out, B);
    }
}

// Round 5
// 194.183 us; speedup vs baseline: 1.7755x; 1.7755x over previous
//
#include <hip/hip_runtime.h>
#include <math.h>

#define EPS 1e-7f

// Native clang vector type — required for __builtin_nontemporal_load.
typedef float f32x4 __attribute__((ext_vector_type(4)));

// Scalar online-softmax update (edge paths only).
__device__ __forceinline__ void online_upd(float x, float& m, float& s) {
    if (x > m) {
        s *= __expf(m - x);
        m = x;
    }
    s += __expf(x - m);
}

// Amortized float4 update: ONE max-compare per 4 elements, 4 independent
// exps, tree-summed. Excludes target column when it falls in this float4.
__device__ __forceinline__ void upd4(const f32x4 x4, int e, int t,
                                     float& m, float& s) {
    if ((unsigned)(t - e) > 3u) {          // common case: target not here
        const float lm = fmaxf(fmaxf(x4.x, x4.y), fmaxf(x4.z, x4.w));
        if (lm > m) {
            s *= __expf(m - lm);           // s==0 first time: exp(-inf)=0 ok
            m = lm;
        }
        const float e0 = __expf(x4.x - m);
        const float e1 = __expf(x4.y - m);
        const float e2 = __expf(x4.z - m);
        const float e3 = __expf(x4.w - m);
        s += (e0 + e1) + (e2 + e3);
    } else {                               // rare: exclude target element
        if (e + 0 != t) online_upd(x4.x, m, s);
        if (e + 1 != t) online_upd(x4.y, m, s);
        if (e + 2 != t) online_upd(x4.z, m, s);
        if (e + 3 != t) online_upd(x4.w, m, s);
    }
}

// Merge (mo, so) into (m, s). Safe when one side is empty (m=-inf, s=0).
__device__ __forceinline__ void merge(float mo, float so, float& m, float& s) {
    const float mn = fmaxf(m, mo);
    s = s * __expf(m - mn) + so * __expf(mo - mn);
    m = mn;
}

// One block per row. Loss is accumulated into a single device-scope float
// accumulator via atomics (NO __threadfence — on MI355X a device fence
// forces per-XCD L2 writeback, which cost +200us in R4). Atomics operate
// at the device-coherent point, so atomic-only communication is safe:
//   each block: atomicAdd(acc, loss) [completed] -> atomicAdd(counter, 1)
//   last ticket: coherent read of acc via atomicAdd(acc, 0.0f).
__global__ __launch_bounds__(256) void cml_fused_kernel(
        const float* __restrict__ in, const int* __restrict__ target,
        float* __restrict__ acc, unsigned* __restrict__ counter,
        float* __restrict__ out, int C, int B) {
    const int row = blockIdx.x;
    const int tid = threadIdx.x;
    const size_t base = (size_t)row * (size_t)C;
    const float* __restrict__ rowp = in + base;
    const int t = target[row];

    float m0 = -INFINITY, s0 = 0.0f;
    float m1 = -INFINITY, s1 = 0.0f;

    // Scalar prologue to 16B alignment (base % 4 == row % 4, C odd).
    const int pre = (4 - (int)(base & 3)) & 3;
    if (tid < pre) {
        if (tid != t) online_upd(rowp[tid], m0, s0);
    }

    const int nv = (C - pre) >> 2;  // aligned float4 count
    const f32x4* __restrict__ v = reinterpret_cast<const f32x4*>(rowp + pre);

    // Unroll-2 with two independent accumulator pairs (R3-proven).
    int j = tid;
    for (; j + 256 < nv; j += 512) {
        const f32x4 a = __builtin_nontemporal_load(&v[j]);
        const f32x4 b = __builtin_nontemporal_load(&v[j + 256]);
        upd4(a, pre + (j << 2),           t, m0, s0);
        upd4(b, pre + ((j + 256) << 2),   t, m1, s1);
    }
    if (j < nv) {
        const f32x4 a = __builtin_nontemporal_load(&v[j]);
        upd4(a, pre + (j << 2), t, m0, s0);
    }

    // Scalar tail.
    for (int k = pre + (nv << 2) + tid; k < C; k += 256) {
        if (k != t) online_upd(rowp[k], m0, s0);
    }

    merge(m1, s1, m0, s0);

    // Wave butterfly reduce of (m0, s0).
    #pragma unroll
    for (int off = 32; off > 0; off >>= 1) {
        const float mo = __shfl_xor(m0, off, 64);
        const float so = __shfl_xor(s0, off, 64);
        merge(mo, so, m0, s0);
    }

    // Cross-wave combine via LDS (4 waves).
    __shared__ float sm[4];
    __shared__ float ss[4];
    if ((tid & 63) == 0) {
        sm[tid >> 6] = m0;
        ss[tid >> 6] = s0;
    }
    __syncthreads();

    if (tid == 0) {
        float M = sm[0], S = ss[0];
        #pragma unroll
        for (int w = 1; w < 4; ++w) merge(sm[w], ss[w], M, S);
        // M = max over non-target, S = sum exp(x - M) over non-target.
        const float xt = rowp[t];
        const float mf = fmaxf(M, xt);
        const float Sf = S * __expf(M - mf) + __expf(xt - mf);
        const float p_t  = __expf(xt - mf) / Sf;
        const float p_mi = __expf(M - mf) / Sf;
        const float loss = -logf(p_t + EPS) - logf(1.0f - p_mi + EPS);

        // Atomic-only handoff. Consume the returned value so the compiler
        // inserts the vmcnt wait BEFORE the ticket atomic issues — this
        // orders acc-add (globally performed) before counter-add.
        const float prev = atomicAdd(acc, loss);
        __asm__ volatile("" :: "v"(prev));
        const unsigned ticket = atomicAdd(counter, 1u);
        if (ticket == (unsigned)(B - 1)) {
            const float total = atomicAdd(acc, 0.0f);  // coherent read
            out[0] = total / (float)B;
        }
    }
}

extern "C" void kernel_launch(void* const* d_in, const int* in_sizes, int n_in,
                              void* d_out, int out_size, void* d_ws, size_t ws_size,
                              hipStream_t stream) {
    const float* in = (const float*)d_in[0];
    const int* target = (const int*)d_in[1];
    const int B = in_sizes[1];                 // 4096
    const int C = in_sizes[0] / B;             // 50257

    float* acc = (float*)d_ws;                 // ws[0]: float accumulator
    unsigned* counter = (unsigned*)((char*)d_ws + sizeof(float));  // ws[1]

    hipMemsetAsync(d_ws, 0, 2 * sizeof(float), stream);
    cml_fused_kernel<<<B, 256, 0, stream>>>(in, target, acc, counter,
                                            (float*)d_out, C, B);
}

// Round 6
// 141.396 us; speedup vs baseline: 2.4383x; 1.3733x over previous
//
#include <hip/hip_runtime.h>
#include <math.h>

#define EPS 1e-7f

// Native clang vector type — required for __builtin_nontemporal_load.
typedef float f32x4 __attribute__((ext_vector_type(4)));

// Scalar online-softmax update (edge paths only).
__device__ __forceinline__ void online_upd(float x, float& m, float& s) {
    if (x > m) {
        s *= __expf(m - x);
        m = x;
    }
    s += __expf(x - m);
}

// Amortized float4 update: ONE max-compare per 4 elements, 4 independent
// exps, tree-summed. Excludes target column when it falls in this float4.
__device__ __forceinline__ void upd4(const f32x4 x4, int e, int t,
                                     float& m, float& s) {
    if ((unsigned)(t - e) > 3u) {          // common case: target not here
        const float lm = fmaxf(fmaxf(x4.x, x4.y), fmaxf(x4.z, x4.w));
        if (lm > m) {
            s *= __expf(m - lm);           // s==0 first time: exp(-inf)=0 ok
            m = lm;
        }
        const float e0 = __expf(x4.x - m);
        const float e1 = __expf(x4.y - m);
        const float e2 = __expf(x4.z - m);
        const float e3 = __expf(x4.w - m);
        s += (e0 + e1) + (e2 + e3);
    } else {                               // rare: exclude target element
        if (e + 0 != t) online_upd(x4.x, m, s);
        if (e + 1 != t) online_upd(x4.y, m, s);
        if (e + 2 != t) online_upd(x4.z, m, s);
        if (e + 3 != t) online_upd(x4.w, m, s);
    }
}

// Merge (mo, so) into (m, s). Safe when one side is empty (m=-inf, s=0).
__device__ __forceinline__ void merge(float mo, float so, float& m, float& s) {
    const float mn = fmaxf(m, mo);
    s = s * __expf(m - mn) + so * __expf(mo - mn);
    m = mn;
}

// One block per row: max & sum-exp EXCLUDING target column, then row loss.
// NO cross-block communication: fences cost +200us (R4), single-address
// device atomics cost +53us (R5) on this 8-XCD chip. Two kernels win.
__global__ __launch_bounds__(256) void cml_row_kernel(
        const float* __restrict__ in, const int* __restrict__ target,
        float* __restrict__ row_loss, int C) {
    const int row = blockIdx.x;
    const int tid = threadIdx.x;
    const size_t base = (size_t)row * (size_t)C;
    const float* __restrict__ rowp = in + base;
    const int t = target[row];

    float m0 = -INFINITY, s0 = 0.0f;
    float m1 = -INFINITY, s1 = 0.0f;

    // Scalar prologue to 16B alignment (base % 4 == row % 4, C odd).
    const int pre = (4 - (int)(base & 3)) & 3;
    if (tid < pre) {
        if (tid != t) online_upd(rowp[tid], m0, s0);
    }

    const int nv = (C - pre) >> 2;  // aligned float4 count
    const f32x4* __restrict__ v = reinterpret_cast<const f32x4*>(rowp + pre);

    // Unroll-2 with two independent accumulator pairs (ILP on the s-chain).
    int j = tid;
    for (; j + 256 < nv; j += 512) {
        const f32x4 a = __builtin_nontemporal_load(&v[j]);
        const f32x4 b = __builtin_nontemporal_load(&v[j + 256]);
        upd4(a, pre + (j << 2),           t, m0, s0);
        upd4(b, pre + ((j + 256) << 2),   t, m1, s1);
    }
    if (j < nv) {
        const f32x4 a = __builtin_nontemporal_load(&v[j]);
        upd4(a, pre + (j << 2), t, m0, s0);
    }

    // Scalar tail.
    for (int k = pre + (nv << 2) + tid; k < C; k += 256) {
        if (k != t) online_upd(rowp[k], m0, s0);
    }

    merge(m1, s1, m0, s0);

    // Wave butterfly reduce of (m0, s0).
    #pragma unroll
    for (int off = 32; off > 0; off >>= 1) {
        const float mo = __shfl_xor(m0, off, 64);
        const float so = __shfl_xor(s0, off, 64);
        merge(mo, so, m0, s0);
    }

    // Cross-wave combine via LDS (4 waves).
    __shared__ float sm[4];
    __shared__ float ss[4];
    if ((tid & 63) == 0) {
        sm[tid >> 6] = m0;
        ss[tid >> 6] = s0;
    }
    __syncthreads();

    if (tid == 0) {
        float M = sm[0], S = ss[0];
        #pragma unroll
        for (int w = 1; w < 4; ++w) merge(sm[w], ss[w], M, S);
        // M = max over non-target, S = sum exp(x - M) over non-target.
        const float xt = rowp[t];
        const float mf = fmaxf(M, xt);
        const float Sf = S * __expf(M - mf) + __expf(xt - mf);
        const float p_t  = __expf(xt - mf) / Sf;
        const float p_mi = __expf(M - mf) / Sf;
        row_loss[row] = -logf(p_t + EPS) - logf(1.0f - p_mi + EPS);
    }
}

// Deterministic single-WAVE mean of B per-row losses (no LDS, no barrier).
__global__ __launch_bounds__(64) void cml_mean_kernel(
        const float* __restrict__ row_loss, float* __restrict__ out, int B) {
    const int tid = threadIdx.x;
    const f32x4* __restrict__ v = reinterpret_cast<const f32x4*>(row_loss);
    float s = 0.0f;
    const int nv = B >> 2;                       // B = 4096 -> 1024 float4s
    for (int i = tid; i < nv; i += 64) {
        const f32x4 x = v[i];
        s += (x.x + x.y) + (x.z + x.w);
    }
    #pragma unroll
    for (int off = 32; off > 0; off >>= 1) s += __shfl_xor(s, off, 64);
    if (tid == 0) out[0] = s / (float)B;
}

extern "C" void kernel_launch(void* const* d_in, const int* in_sizes, int n_in,
                              void* d_out, int out_size, void* d_ws, size_t ws_size,
                              hipStream_t stream) {
    const float* in = (const float*)d_in[0];
    const int* target = (const int*)d_in[1];
    const int B = in_sizes[1];                 // 4096
    const int C = in_sizes[0] / B;             // 50257
    float* row_loss = (float*)d_ws;            // B floats of scratch

    cml_row_kernel<<<B, 256, 0, stream>>>(in, target, row_loss, C);
    cml_mean_kernel<<<1, 64, 0, stream>>>(row_loss, (float*)d_out, B);
}